// Round 16
// baseline (229.265 us; speedup 1.0000x reference)
//
#include <hip/hip_runtime.h>

typedef unsigned short ushort_t;
typedef __attribute__((ext_vector_type(8))) short short8;   // 8 bf16 (4 VGPRs)
typedef __attribute__((ext_vector_type(4))) float floatx4;  // 4 fp32 acc

#define B_  4
#define T_  2048
#define C_  512
#define H_  8
#define HS_ 64
#define M_  (B_*T_)          // 8192 rows
// score scale with log2(e) folded in (exp2 path): 512^-0.5 * 1.442695
// folded into wq during prep_k (fp32 multiply pre-bf16-round).
#define SCALE2 0.06376140168547404f

__device__ __forceinline__ float b2f(ushort_t u) {
  union { unsigned int i; float f; } w; w.i = ((unsigned int)u) << 16; return w.f;
}
__device__ __forceinline__ ushort_t f2b(float f) {
  union { float f; unsigned int i; } w; w.f = f;
  unsigned int x = w.i;
  return (ushort_t)((x + 0x7fffu + ((x >> 16) & 1u)) >> 16);  // RNE
}
// v_cvt_pk_bf16_f32: pack two f32 -> u32 of {lo=bf16(a), hi=bf16(b)}
__device__ __forceinline__ unsigned int cvtpk(float a, float b) {
  unsigned int r;
  asm("v_cvt_pk_bf16_f32 %0, %1, %2" : "=v"(r) : "v"(a), "v"(b));
  return r;
}
// async global->LDS, 16B per lane; LDS dest = (uniform base) + lane*16B
__device__ __forceinline__ void gl_lds16(const ushort_t* g, ushort_t* l) {
  __builtin_amdgcn_global_load_lds((const unsigned int*)g, (unsigned int*)l, 16, 0, 0);
}

// ---- fused prep: weight transposes + LN1 in one dispatch ------------------
__global__ __launch_bounds__(256) void prep_k(const float* __restrict__ wq,
                                              const float* __restrict__ wk,
                                              const float* __restrict__ wv,
                                              const float* __restrict__ w1,
                                              const float* __restrict__ w2,
                                              ushort_t* __restrict__ qkvt,
                                              ushort_t* __restrict__ w1t,
                                              ushort_t* __restrict__ w2t,
                                              const float* __restrict__ X,
                                              const float* __restrict__ lg,
                                              const float* __restrict__ lb,
                                              ushort_t* __restrict__ Y) {
  int idx = blockIdx.x;
  if (idx >= 2816) {                    // ---- LN1 part ----
    int wave = threadIdx.x >> 6, lane = threadIdx.x & 63;
    size_t row = (size_t)(idx - 2816) * 4 + wave;
    float v[8], s = 0.f, s2 = 0.f;
#pragma unroll
    for (int i = 0; i < 8; i++) {
      float x = X[row * C_ + lane + 64 * i];
      v[i] = x; s += x; s2 += x * x;
    }
#pragma unroll
    for (int off = 32; off >= 1; off >>= 1) {
      s += __shfl_xor(s, off); s2 += __shfl_xor(s2, off);
    }
    float mu = s * (1.0f / C_);
    float var = s2 * (1.0f / C_) - mu * mu;
    float rs = rsqrtf(var + 1e-5f);
    ushort_t* yr = Y + row * C_;
#pragma unroll
    for (int i = 0; i < 8; i++) {
      int c = lane + 64 * i;
      yr[c] = f2b((v[i] - mu) * rs * lg[c] + lb[c]);
    }
    return;
  }
  // ---- transpose part ----
  __shared__ ushort_t t[32][33];
  const float* in; ushort_t* out; int K, N, bx, by, z = 0;
  float scl = (idx < 256) ? SCALE2 : 1.0f;   // seg 0 == wq
  if (idx < 768) {
    int seg = idx >> 8, li = idx & 255;
    in = seg == 0 ? wq : (seg == 1 ? wk : wv);
    out = qkvt + (size_t)seg * 262144;
    K = 512; N = 64;
    z = li >> 5; li &= 31;
    bx = li & 1; by = li >> 1;
  } else if (idx < 1792) {
    int li = idx - 768;
    in = w1; out = w1t; K = 512; N = 2048;
    bx = li & 63; by = li >> 6;
  } else {
    int li = idx - 1792;
    in = w2; out = w2t; K = 2048; N = 512;
    bx = li & 15; by = li >> 4;
  }
  size_t zoff = (size_t)z * K * N;
  int n0 = bx * 32, k0 = by * 32;
  int tx = threadIdx.x & 31, ty = threadIdx.x >> 5;
#pragma unroll
  for (int i = 0; i < 4; i++)
    t[ty + 8 * i][tx] = f2b(in[zoff + (size_t)(k0 + ty + 8 * i) * N + n0 + tx] * scl);
  __syncthreads();
#pragma unroll
  for (int i = 0; i < 4; i++)
    out[zoff + (size_t)(n0 + ty + 8 * i) * K + k0 + tx] = t[tx][ty + 8 * i];
}

// ---- LayerNorm: wave per row of 512 (fp32 in, bf16 out) ------------------
__global__ __launch_bounds__(256) void ln_k(const float* __restrict__ X,
                                            const float* __restrict__ g,
                                            const float* __restrict__ bb,
                                            ushort_t* __restrict__ Y) {
  int wave = threadIdx.x >> 6, lane = threadIdx.x & 63;
  size_t row = (size_t)blockIdx.x * 4 + wave;
  float v[8], s = 0.f, s2 = 0.f;
#pragma unroll
  for (int i = 0; i < 8; i++) {
    float x = X[row * C_ + lane + 64 * i];
    v[i] = x; s += x; s2 += x * x;
  }
#pragma unroll
  for (int off = 32; off >= 1; off >>= 1) {
    s += __shfl_xor(s, off); s2 += __shfl_xor(s2, off);
  }
  float mu = s * (1.0f / C_);
  float var = s2 * (1.0f / C_) - mu * mu;
  float rs = rsqrtf(var + 1e-5f);
  ushort_t* yr = Y + row * C_;
#pragma unroll
  for (int i = 0; i < 8; i++) {
    int c = lane + 64 * i;
    yr[c] = f2b((v[i] - mu) * rs * g[c] + bb[c]);
  }
}

// ---- GEMM 128x128, 4 waves, wave-tile 64x64, dbuf, ONE barrier/K-step ----
// LDS-read-ratio fix: 8-wave dbuf (wave-tile 64x32) reads 6 ds_read_b128
// per 8 MFMA = 1.33; this 4-wave acc[4][4] shape reads 8 per 16 = 2.0 --
// the r0 gemm_bt128 compute (proven) grafted onto the proven dbuf skeleton.
// Same 64KB LDS (2 blocks/CU = 2 waves/SIMD residency unchanged vs r15).
__global__ __launch_bounds__(256) void gemm_dbuf4(const ushort_t* __restrict__ A,
                                                  const ushort_t* __restrict__ Bt,
                                                  ushort_t* __restrict__ Out,
                                                  int K, int ldOut,
                                                  const float* __restrict__ bias,
                                                  int relu) {
  __shared__ __align__(16) ushort_t As[2][128 * 64];
  __shared__ __align__(16) ushort_t Bs[2][128 * 64];
  const int tid = threadIdx.x;
  const int lane = tid & 63, wave = tid >> 6;       // 4 waves
  const long row0 = (long)blockIdx.x * 128;         // row-fast
  const long col0 = (long)blockIdx.y * 128;
  const int srow = wave * 32 + (lane >> 3);         // +i*8 -> rows 0..127
  const int scol = (((lane & 7) ^ ((lane >> 3) & 7))) * 8;   // swizzled source
  const ushort_t* Ab = A + (size_t)(row0 + srow) * K + scol;
  const ushort_t* Bb = Bt + (size_t)(col0 + srow) * K + scol;
  const int wm = (wave >> 1) * 64, wn = (wave & 1) * 64;     // wave-tile 64x64
  const int fq = lane >> 4, fl = lane & 15;
  floatx4 acc[4][4] = {};

  // prologue: stage K-tile 0 into buffer 0 (8 gl_lds16 per wave)
#pragma unroll
  for (int i = 0; i < 4; i++) {
    gl_lds16(Ab + (size_t)(i * 8) * K, &As[0][(wave * 32 + i * 8) * 64]);
    gl_lds16(Bb + (size_t)(i * 8) * K, &Bs[0][(wave * 32 + i * 8) * 64]);
  }
  __syncthreads();

  int cur = 0;
  for (int k0 = 0; k0 < K; k0 += 64) {
    const int nk = k0 + 64;
    if (nk < K) {                       // issue next tile's loads (async)
      const int nb = cur ^ 1;
#pragma unroll
      for (int i = 0; i < 4; i++) {
        gl_lds16(Ab + (size_t)(i * 8) * K + nk, &As[nb][(wave * 32 + i * 8) * 64]);
        gl_lds16(Bb + (size_t)(i * 8) * K + nk, &Bs[nb][(wave * 32 + i * 8) * 64]);
      }
    }
#pragma unroll
    for (int ks = 0; ks < 2; ks++) {
      short8 af[4], bf[4];
      const int sl = ((ks * 4 + fq) ^ (fl & 7)) * 8;
#pragma unroll
      for (int i = 0; i < 4; i++) {
        af[i] = *(const short8*)&As[cur][(wm + i * 16 + fl) * 64 + sl];
        bf[i] = *(const short8*)&Bs[cur][(wn + i * 16 + fl) * 64 + sl];
      }
#pragma unroll
      for (int fi = 0; fi < 4; fi++)
#pragma unroll
        for (int fj = 0; fj < 4; fj++)
          acc[fi][fj] = __builtin_amdgcn_mfma_f32_16x16x32_bf16(af[fi], bf[fj], acc[fi][fj], 0, 0, 0);
    }
    __syncthreads();                    // drains prefetch; protects swap
    cur ^= 1;
  }
#pragma unroll
  for (int fi = 0; fi < 4; fi++)
#pragma unroll
    for (int fj = 0; fj < 4; fj++) {
      long gcol = col0 + wn + fj * 16 + fl;
      float bv = bias ? bias[gcol] : 0.0f;
#pragma unroll
      for (int r = 0; r < 4; r++) {
        long grow = row0 + wm + fi * 16 + fq * 4 + r;
        float v = acc[fi][fj][r] + bv;
        if (relu) v = fmaxf(v, 0.0f);
        Out[(size_t)grow * ldOut + gcol] = f2b(v);
      }
    }
}

// ---- FFN2 GEMM: 128^2, K=2048, counted-vmcnt schedule (r15-proven) -------
__global__ __launch_bounds__(512) void gemm_ffn2(const ushort_t* __restrict__ A,
                                                 const ushort_t* __restrict__ Bt,
                                                 float* __restrict__ Out,
                                                 const float* __restrict__ bias,
                                                 const float* __restrict__ residual) {
  const int K = 2048, ldOut = 512;
  __shared__ __align__(16) ushort_t As[2][128 * 64];
  __shared__ __align__(16) ushort_t Bs[2][128 * 64];
  const int tid = threadIdx.x;
  const int lane = tid & 63, wave = tid >> 6;       // 8 waves
  const long row0 = (long)blockIdx.x * 128;         // row-fast
  const long col0 = (long)blockIdx.y * 128;
  const int srow = wave * 16 + (lane >> 3);
  const int scol = (((lane & 7) ^ ((lane >> 3) & 7))) * 8;
  const ushort_t* Ab = A + (size_t)(row0 + srow) * K + scol;
  const ushort_t* Bb = Bt + (size_t)(col0 + srow) * K + scol;
  const int wm = (wave >> 2) * 64, wn = (wave & 3) * 32;
  const int fq = lane >> 4, fl = lane & 15;
  floatx4 acc[4][2] = {};

  // prologue: issue L(0) into buffer 0 (4 VMEM ops/wave); no sync here --
  // iteration 0's vmcnt+B2 handles it.
#pragma unroll
  for (int i = 0; i < 2; i++) {
    gl_lds16(Ab + (size_t)(i * 8) * K, &As[0][(wave * 16 + i * 8) * 64]);
    gl_lds16(Bb + (size_t)(i * 8) * K, &Bs[0][(wave * 16 + i * 8) * 64]);
  }

  int cur = 0;
  for (int k0 = 0; k0 < K; k0 += 64) {
    __builtin_amdgcn_s_barrier();       // B1: all waves done reading buf[cur^1]
    const int nk = k0 + 64;
    if (nk < K) {                       // issue L(t+1) -> buf[cur^1]
      const int nb = cur ^ 1;
#pragma unroll
      for (int i = 0; i < 2; i++) {
        gl_lds16(Ab + (size_t)(i * 8) * K + nk, &As[nb][(wave * 16 + i * 8) * 64]);
        gl_lds16(Bb + (size_t)(i * 8) * K + nk, &Bs[nb][(wave * 16 + i * 8) * 64]);
      }
      asm volatile("s_waitcnt vmcnt(4)" ::: "memory");  // t-batch landed
    } else {
      asm volatile("s_waitcnt vmcnt(0)" ::: "memory");  // final batch landed
    }
    __builtin_amdgcn_s_barrier();       // B2: buf[cur] staged by all waves
#pragma unroll
    for (int ks = 0; ks < 2; ks++) {
      short8 af[4], bf[2];
      const int sl = ((ks * 4 + fq) ^ (fl & 7)) * 8;
#pragma unroll
      for (int i = 0; i < 4; i++)
        af[i] = *(const short8*)&As[cur][(wm + i * 16 + fl) * 64 + sl];
#pragma unroll
      for (int j = 0; j < 2; j++)
        bf[j] = *(const short8*)&Bs[cur][(wn + j * 16 + fl) * 64 + sl];
#pragma unroll
      for (int fi = 0; fi < 4; fi++)
#pragma unroll
        for (int fj = 0; fj < 2; fj++)
          acc[fi][fj] = __builtin_amdgcn_mfma_f32_16x16x32_bf16(af[fi], bf[fj], acc[fi][fj], 0, 0, 0);
    }
    cur ^= 1;
  }
#pragma unroll
  for (int fi = 0; fi < 4; fi++)
#pragma unroll
    for (int fj = 0; fj < 2; fj++) {
      long gcol = col0 + wn + fj * 16 + fl;
      float bv = bias[gcol];
#pragma unroll
      for (int r = 0; r < 4; r++) {
        long grow = row0 + wm + fi * 16 + fq * 4 + r;
        size_t oi = (size_t)grow * ldOut + gcol;
        Out[oi] = acc[fi][fj][r] + bv + residual[oi];
      }
    }
}

// ---- GEMM 64x64 (FFN2 fallback): fp32 out = acc + bias + residual --------
__global__ __launch_bounds__(256) void gemm_bt64(const ushort_t* __restrict__ A,
                                                 const ushort_t* __restrict__ Bt,
                                                 float* __restrict__ Out,
                                                 int K, int ldOut,
                                                 const float* __restrict__ bias,
                                                 const float* __restrict__ residual) {
  __shared__ __align__(16) ushort_t As[64 * 64];
  __shared__ __align__(16) ushort_t Bs[64 * 64];
  const int tid = threadIdx.x;
  const int lane = tid & 63, wave = tid >> 6;
  const long row0 = (long)blockIdx.x * 64;    // row-fast
  const long col0 = (long)blockIdx.y * 64;
  const int srow = wave * 16 + (lane >> 3);
  const int scol = (((lane & 7) ^ ((lane >> 3) & 7))) * 8;
  const ushort_t* Ab = A + (size_t)(row0 + srow) * K + scol;
  const ushort_t* Bb = Bt + (size_t)(col0 + srow) * K + scol;
  const int wm = (wave >> 1) * 32, wn = (wave & 1) * 32;
  const int fq = lane >> 4, fl = lane & 15;
  floatx4 acc[2][2] = {};

  for (int k0 = 0; k0 < K; k0 += 64) {
    __syncthreads();
#pragma unroll
    for (int i = 0; i < 2; i++) {
      gl_lds16(Ab + (size_t)(i * 8) * K + k0, &As[(wave * 16 + i * 8) * 64]);
      gl_lds16(Bb + (size_t)(i * 8) * K + k0, &Bs[(wave * 16 + i * 8) * 64]);
    }
    __syncthreads();
#pragma unroll
    for (int ks = 0; ks < 2; ks++) {
      short8 af[2], bf[2];
      const int sl = ((ks * 4 + fq) ^ (fl & 7)) * 8;
#pragma unroll
      for (int i = 0; i < 2; i++) {
        af[i] = *(const short8*)&As[(wm + i * 16 + fl) * 64 + sl];
        bf[i] = *(const short8*)&Bs[(wn + i * 16 + fl) * 64 + sl];
      }
#pragma unroll
      for (int fi = 0; fi < 2; fi++)
#pragma unroll
        for (int fj = 0; fj < 2; fj++)
          acc[fi][fj] = __builtin_amdgcn_mfma_f32_16x16x32_bf16(af[fi], bf[fj], acc[fi][fj], 0, 0, 0);
    }
  }
#pragma unroll
  for (int fi = 0; fi < 2; fi++)
#pragma unroll
    for (int fj = 0; fj < 2; fj++) {
      long gcol = col0 + wn + fj * 16 + fl;
      float bv = bias[gcol];
#pragma unroll
      for (int r = 0; r < 4; r++) {
        long grow = row0 + wm + fi * 16 + fq * 4 + r;
        size_t oi = (size_t)grow * ldOut + gcol;
        Out[oi] = acc[fi][fj][r] + bv + residual[oi];
      }
    }
}

// ---- flash attention + residual, 64-row q-tiles, 256 threads (4 waves) ---
// Round-3 proven structure + isolated T5 setprio (r14/r15: 49.2-49.4 us,
// 60 VGPR -- best measured; kept).
__global__ __launch_bounds__(256) void flash_attn(const ushort_t* __restrict__ QKV,
                                                  const float* __restrict__ X,
                                                  float* __restrict__ X1) {
  __shared__ __align__(16) ushort_t kt[2][64 * 72];   // [s][d]
  __shared__ __align__(16) ushort_t vt[2][64 * 72];   // [d][s^swz]
  const int tid = threadIdx.x;
  const int lane = tid & 63, wave = tid >> 6;      // 4 waves
  const int fq = lane >> 4, fl = lane & 15;
  const int g = blockIdx.x >> 5;                   // 0..31
  const int tile = g < 16 ? 31 - g : g - 16;       // balanced pairing
  const int bh = blockIdx.x & 31;
  const int h = bh & 7, b = bh >> 3;
  const int hoff = h * HS_;
  const int q0 = tile * 64;
  const int LD = 3 * C_;                           // 1536
  const int nst = tile + 1;
  const int qg = q0 + wave * 16 + fl;              // q owned by this lane (S^T col)

  short8 qf0, qf1;
  {
    const ushort_t* qp = QKV + (size_t)((size_t)b * T_ + q0 + wave * 16 + fl) * LD + hoff + fq * 8;
    qf0 = *(const short8*)(qp);
    qf1 = *(const short8*)(qp + 32);
  }
  // ones B-fragment for l-accumulation: B[s][d']=1 iff d'==0  -> col fl==0
  short8 of;
  {
    short ob = (fl == 0) ? (short)0x3F80 : (short)0;
#pragma unroll
    for (int i = 0; i < 8; i++) of[i] = ob;
  }
  floatx4 oacc[4] = {};
  floatx4 lacc = {};

  // staging roles: waves 0..1 stage V (transposed), waves 2..3 stage K.
  const int role = tid >> 7;            // 0: V, 1: K
  const int t2 = tid & 127;
  const int sr4 = (t2 >> 3) * 4;        // 0,4,..,60
  const int d0 = (t2 & 7) * 8;          // 0..56
  const ushort_t* sbase = QKV + (size_t)((size_t)b * T_ + sr4) * LD + hoff +
                          (role ? C_ : 2 * C_);   // K at +C_, V at +2C_

  // bpermute source byte-addresses (lane*4)
  const int addrA = ((2 * (fq & 1)) * 16 + fl) * 4;
  const int addrB = addrA + 64;
  const bool lowq = fq < 2;             // dest half selects chunk c=2o vs 2o+1

  // prefetch + stage s-tile 0 into buffer 0
  short8 r0 = *(const short8*)(sbase + d0);
  short8 r1 = *(const short8*)(sbase + LD + d0);
  short8 r2 = *(const short8*)(sbase + 2 * LD + d0);
  short8 r3 = *(const short8*)(sbase + 3 * LD + d0);
  if (role) {
    *(short8*)&kt[0][sr4 * 72 + d0] = r0;
    *(short8*)&kt[0][(sr4 + 1) * 72 + d0] = r1;
    *(short8*)&kt[0][(sr4 + 2) * 72 + d0] = r2;
    *(short8*)&kt[0][(sr4 + 3) * 72 + d0] = r3;
  } else {
#pragma unroll
    for (int i = 0; i < 8; i++) {
      int d = d0 + i;
      int scol = sr4 ^ (8 * (d >> 3));
      unsigned int pkA = ((unsigned int)(ushort_t)r0[i]) |
                         (((unsigned int)(ushort_t)r1[i]) << 16);
      unsigned int pkB = ((unsigned int)(ushort_t)r2[i]) |
                         (((unsigned int)(ushort_t)r3[i]) << 16);
      *(unsigned int*)&vt[0][d * 72 + scol] = pkA;
      *(unsigned int*)&vt[0][d * 72 + scol + 2] = pkB;
    }
  }
  {  // prefetch s-tile 1 (safe even when nst==1: rows 64..127 < T)
    const ushort_t* sp = sbase + (size_t)64 * LD;
    r0 = *(const short8*)(sp + d0);
    r1 = *(const short8*)(sp + LD + d0);
    r2 = *(const short8*)(sp + 2 * LD + d0);
    r3 = *(const short8*)(sp + 3 * LD + d0);
  }

  for (int st = 0; st < nst; st++) {
    __syncthreads();                    // buf[st&1] staged; compute(st-1) done
    const int cur = st & 1;
    if (st + 1 < nst) {                 // stage next tile into other buffer
      const int nb = cur ^ 1;
      if (role) {
        *(short8*)&kt[nb][sr4 * 72 + d0] = r0;
        *(short8*)&kt[nb][(sr4 + 1) * 72 + d0] = r1;
        *(short8*)&kt[nb][(sr4 + 2) * 72 + d0] = r2;
        *(short8*)&kt[nb][(sr4 + 3) * 72 + d0] = r3;
      } else {
#pragma unroll
        for (int i = 0; i < 8; i++) {
          int d = d0 + i;
          int scol = sr4 ^ (8 * (d >> 3));
          unsigned int pkA = ((unsigned int)(ushort_t)r0[i]) |
                             (((unsigned int)(ushort_t)r1[i]) << 16);
          unsigned int pkB = ((unsigned int)(ushort_t)r2[i]) |
                             (((unsigned int)(ushort_t)r3[i]) << 16);
          *(unsigned int*)&vt[nb][d * 72 + scol] = pkA;
          *(unsigned int*)&vt[nb][d * 72 + scol + 2] = pkB;
        }
      }
      if (st + 2 < nst) {               // issue loads for tile st+2
        const ushort_t* sp = sbase + (size_t)(st + 2) * 64 * LD;
        r0 = *(const short8*)(sp + d0);
        r1 = *(const short8*)(sp + LD + d0);
        r2 = *(const short8*)(sp + 2 * LD + d0);
        r3 = *(const short8*)(sp + 3 * LD + d0);
      }
    }

    {
      const int s0 = st * 64;
      floatx4 sacc[4] = {};
      __builtin_amdgcn_s_setprio(1);
#pragma unroll
      for (int fn = 0; fn < 4; fn++) {
        short8 kf0 = *(const short8*)&kt[cur][(fn * 16 + fl) * 72 + fq * 8];
        short8 kf1 = *(const short8*)&kt[cur][(fn * 16 + fl) * 72 + 32 + fq * 8];
        // swapped: A=K rows s, B=Q cols q  ->  D = S^T[s][q]
        sacc[fn] = __builtin_amdgcn_mfma_f32_16x16x32_bf16(kf0, qf0, sacc[fn], 0, 0, 0);
        sacc[fn] = __builtin_amdgcn_mfma_f32_16x16x32_bf16(kf1, qf1, sacc[fn], 0, 0, 0);
      }
      __builtin_amdgcn_s_setprio(0);
      const bool diag = (st == tile);
      unsigned int xc[4][2];            // pair (8*fn + 2*fq + j) of P[q=fl][*]
#pragma unroll
      for (int fn = 0; fn < 4; fn++) {
        float p[4];
#pragma unroll
        for (int r = 0; r < 4; r++) {
          float pv = exp2f(sacc[fn][r]);        // scale folded into wq
          if (diag && (s0 + fn * 16 + fq * 4 + r) > qg) pv = 0.0f;
          p[r] = pv;
        }
        xc[fn][0] = cvtpk(p[0], p[1]);
        xc[fn][1] = cvtpk(p[2], p[3]);
      }
      // in-register layout conversion -> PV A-fragments
      union U8 { unsigned int u[4]; short8 s8; } pu[2];
#pragma unroll
      for (int o = 0; o < 2; o++)
#pragma unroll
        for (int t = 0; t < 4; t++) {
          int ad = (t >> 1) ? addrB : addrA;
          int lo = __builtin_amdgcn_ds_bpermute(ad, (int)xc[2 * o][t & 1]);
          int hi = __builtin_amdgcn_ds_bpermute(ad, (int)xc[2 * o + 1][t & 1]);
          pu[o].u[t] = lowq ? (unsigned int)lo : (unsigned int)hi;
        }
      short8 pf0 = pu[0].s8, pf1 = pu[1].s8;
      __builtin_amdgcn_s_setprio(1);
#pragma unroll
      for (int fn = 0; fn < 4; fn++) {
        int drow = fn * 16 + fl;
        int sw = 8 * (drow >> 3);
        short8 vf0 = *(const short8*)&vt[cur][drow * 72 + ((fq * 8) ^ sw)];
        short8 vf1 = *(const short8*)&vt[cur][drow * 72 + ((32 + fq * 8) ^ sw)];
        oacc[fn] = __builtin_amdgcn_mfma_f32_16x16x32_bf16(pf0, vf0, oacc[fn], 0, 0, 0);
        oacc[fn] = __builtin_amdgcn_mfma_f32_16x16x32_bf16(pf1, vf1, oacc[fn], 0, 0, 0);
      }
      lacc = __builtin_amdgcn_mfma_f32_16x16x32_bf16(pf0, of, lacc, 0, 0, 0);
      lacc = __builtin_amdgcn_mfma_f32_16x16x32_bf16(pf1, of, lacc, 0, 0, 0);
      __builtin_amdgcn_s_setprio(0);
    }
  }
  // X1 = X + O/l
#pragma unroll
  for (int r = 0; r < 4; r++) {
    float lr = __shfl(lacc[r], lane & 48);
    float inv = 1.0f / lr;
    int qgr = q0 + wave * 16 + fq * 4 + r;
#pragma unroll
    for (int fn = 0; fn < 4; fn++) {
      int d = fn * 16 + fl;
      size_t oi = ((size_t)b * T_ + qgr) * C_ + hoff + d;
      X1[oi] = oacc[fn][r] * inv + X[oi];
    }
  }
}

extern "C" void kernel_launch(void* const* d_in, const int* in_sizes, int n_in,
                              void* d_out, int out_size, void* d_ws, size_t ws_size,
                              hipStream_t stream) {
  const float* x  = (const float*)d_in[0];
  const float* wq = (const float*)d_in[1];
  const float* wk = (const float*)d_in[2];
  const float* wv = (const float*)d_in[3];
  const float* w1 = (const float*)d_in[4];
  const float* b1 = (const float*)d_in[5];
  const float* w2 = (const float*)d_in[6];
  const float* b2 = (const float*)d_in[7];
  const float* ln1g = (const float*)d_in[8];
  const float* ln1b = (const float*)d_in[9];
  const float* ln2g = (const float*)d_in[10];
  const float* ln2b = (const float*)d_in[11];
  ushort_t* ws = (ushort_t*)d_ws;

  const size_t SZ = (size_t)M_ * C_;   // 4,194,304 elems
  // ws base: qkvt 786432 | w1t 1048576 | w2t 1048576 | qkv region
  //   split path:   qkv 3*SZ (30.9 MB total); h2=qkv[0,SZ), ff1=qkv[SZ,3SZ)
  //   unsplit path: qkv region 5*SZ (47.7 MB total); ff1=qkv[SZ,5SZ) full-M
  ushort_t* qkvt = ws;
  ushort_t* w1t  = qkvt + 786432;
  ushort_t* w2t  = w1t + 1048576;
  ushort_t* qkv  = w2t + 1048576;
  ushort_t* h2   = qkv;
  ushort_t* ff1  = qkv + SZ;
  ushort_t* h    = (ushort_t*)d_out;   // LN1 out (bf16); dead before flash
  float* x1      = (float*)d_out;      // fp32 residual-1 & final out
  float* outf    = (float*)d_out;

  const size_t need_unsplit = (2883584 + 5 * SZ) * sizeof(ushort_t);  // 47.7 MB

  // fused: weight transposes (2816 blocks) + LN1 (2048 blocks)
  prep_k<<<2816 + M_ / 4, 256, 0, stream>>>(wq, wk, wv, w1, w2, qkvt, w1t, w2t,
                                            x, ln1g, ln1b, h);
  // fused QKV: 128^2 tiles, 4-wave acc[4][4] dbuf, 64x12 = 768 blocks
  gemm_dbuf4<<<dim3(64, 12), 256, 0, stream>>>(h, qkvt, qkv, 512, 1536,
                                               nullptr, 0);
  // attention + residual -> x1; 1024 blocks x 256 threads, balanced tiles
  flash_attn<<<B_ * H_ * (T_ / 64), 256, 0, stream>>>(qkv, x, x1);
  ln_k<<<M_ / 4, 256, 0, stream>>>(x1, ln2g, ln2b, h2);
  if (ws_size >= need_unsplit) {
    // FFN1: 4-wave acc[4][4] dbuf, 64x16 = 1024 blocks;
    // FFN2: 128^2, 64x4 = 256 blocks, counted-vmcnt schedule (r15)
    gemm_dbuf4<<<dim3(64, 16), 256, 0, stream>>>(h2, w1t, ff1, 512, 2048, b1, 1);
    gemm_ffn2<<<dim3(64, 4), 512, 0, stream>>>(ff1, w2t, outf, b2, x1);
  } else {
    for (int p = 0; p < 2; p++) {
      const size_t roff = (size_t)p * 4096;
      gemm_dbuf4<<<dim3(32, 16), 256, 0, stream>>>(h2 + roff * C_, w1t, ff1,
                                                   512, 2048, b1, 1);
      gemm_bt64<<<dim3(64, 8), 256, 0, stream>>>(ff1, w2t, outf + roff * C_,
                                                 2048, 512, b2, x1 + roff * C_);
    }
  }
}

// Round 17
// 224.703 us; speedup vs baseline: 1.0203x; 1.0203x over previous
//
#include <hip/hip_runtime.h>

typedef unsigned short ushort_t;
typedef __attribute__((ext_vector_type(8))) short short8;   // 8 bf16 (4 VGPRs)
typedef __attribute__((ext_vector_type(4))) float floatx4;  // 4 fp32 acc

#define B_  4
#define T_  2048
#define C_  512
#define H_  8
#define HS_ 64
#define M_  (B_*T_)          // 8192 rows
// score scale with log2(e) folded in (exp2 path): 512^-0.5 * 1.442695
// folded into wq during prep_k (fp32 multiply pre-bf16-round).
#define SCALE2 0.06376140168547404f

__device__ __forceinline__ float b2f(ushort_t u) {
  union { unsigned int i; float f; } w; w.i = ((unsigned int)u) << 16; return w.f;
}
__device__ __forceinline__ ushort_t f2b(float f) {
  union { float f; unsigned int i; } w; w.f = f;
  unsigned int x = w.i;
  return (ushort_t)((x + 0x7fffu + ((x >> 16) & 1u)) >> 16);  // RNE
}
// v_cvt_pk_bf16_f32: pack two f32 -> u32 of {lo=bf16(a), hi=bf16(b)}
__device__ __forceinline__ unsigned int cvtpk(float a, float b) {
  unsigned int r;
  asm("v_cvt_pk_bf16_f32 %0, %1, %2" : "=v"(r) : "v"(a), "v"(b));
  return r;
}
// async global->LDS, 16B per lane; LDS dest = (uniform base) + lane*16B
__device__ __forceinline__ void gl_lds16(const ushort_t* g, ushort_t* l) {
  __builtin_amdgcn_global_load_lds((const unsigned int*)g, (unsigned int*)l, 16, 0, 0);
}

// ---- fused prep: weight transposes + LN1 in one dispatch ------------------
__global__ __launch_bounds__(256) void prep_k(const float* __restrict__ wq,
                                              const float* __restrict__ wk,
                                              const float* __restrict__ wv,
                                              const float* __restrict__ w1,
                                              const float* __restrict__ w2,
                                              ushort_t* __restrict__ qkvt,
                                              ushort_t* __restrict__ w1t,
                                              ushort_t* __restrict__ w2t,
                                              const float* __restrict__ X,
                                              const float* __restrict__ lg,
                                              const float* __restrict__ lb,
                                              ushort_t* __restrict__ Y) {
  int idx = blockIdx.x;
  if (idx >= 2816) {                    // ---- LN1 part ----
    int wave = threadIdx.x >> 6, lane = threadIdx.x & 63;
    size_t row = (size_t)(idx - 2816) * 4 + wave;
    float v[8], s = 0.f, s2 = 0.f;
#pragma unroll
    for (int i = 0; i < 8; i++) {
      float x = X[row * C_ + lane + 64 * i];
      v[i] = x; s += x; s2 += x * x;
    }
#pragma unroll
    for (int off = 32; off >= 1; off >>= 1) {
      s += __shfl_xor(s, off); s2 += __shfl_xor(s2, off);
    }
    float mu = s * (1.0f / C_);
    float var = s2 * (1.0f / C_) - mu * mu;
    float rs = rsqrtf(var + 1e-5f);
    ushort_t* yr = Y + row * C_;
#pragma unroll
    for (int i = 0; i < 8; i++) {
      int c = lane + 64 * i;
      yr[c] = f2b((v[i] - mu) * rs * lg[c] + lb[c]);
    }
    return;
  }
  // ---- transpose part ----
  __shared__ ushort_t t[32][33];
  const float* in; ushort_t* out; int K, N, bx, by, z = 0;
  float scl = (idx < 256) ? SCALE2 : 1.0f;   // seg 0 == wq
  if (idx < 768) {
    int seg = idx >> 8, li = idx & 255;
    in = seg == 0 ? wq : (seg == 1 ? wk : wv);
    out = qkvt + (size_t)seg * 262144;
    K = 512; N = 64;
    z = li >> 5; li &= 31;
    bx = li & 1; by = li >> 1;
  } else if (idx < 1792) {
    int li = idx - 768;
    in = w1; out = w1t; K = 512; N = 2048;
    bx = li & 63; by = li >> 6;
  } else {
    int li = idx - 1792;
    in = w2; out = w2t; K = 2048; N = 512;
    bx = li & 15; by = li >> 4;
  }
  size_t zoff = (size_t)z * K * N;
  int n0 = bx * 32, k0 = by * 32;
  int tx = threadIdx.x & 31, ty = threadIdx.x >> 5;
#pragma unroll
  for (int i = 0; i < 4; i++)
    t[ty + 8 * i][tx] = f2b(in[zoff + (size_t)(k0 + ty + 8 * i) * N + n0 + tx] * scl);
  __syncthreads();
#pragma unroll
  for (int i = 0; i < 4; i++)
    out[zoff + (size_t)(n0 + ty + 8 * i) * K + k0 + tx] = t[tx][ty + 8 * i];
}

// ---- LayerNorm: wave per row of 512 (fp32 in, bf16 out) ------------------
__global__ __launch_bounds__(256) void ln_k(const float* __restrict__ X,
                                            const float* __restrict__ g,
                                            const float* __restrict__ bb,
                                            ushort_t* __restrict__ Y) {
  int wave = threadIdx.x >> 6, lane = threadIdx.x & 63;
  size_t row = (size_t)blockIdx.x * 4 + wave;
  float v[8], s = 0.f, s2 = 0.f;
#pragma unroll
  for (int i = 0; i < 8; i++) {
    float x = X[row * C_ + lane + 64 * i];
    v[i] = x; s += x; s2 += x * x;
  }
#pragma unroll
  for (int off = 32; off >= 1; off >>= 1) {
    s += __shfl_xor(s, off); s2 += __shfl_xor(s2, off);
  }
  float mu = s * (1.0f / C_);
  float var = s2 * (1.0f / C_) - mu * mu;
  float rs = rsqrtf(var + 1e-5f);
  ushort_t* yr = Y + row * C_;
#pragma unroll
  for (int i = 0; i < 8; i++) {
    int c = lane + 64 * i;
    yr[c] = f2b((v[i] - mu) * rs * g[c] + bb[c]);
  }
}

// ---- GEMM 128x128, 8 waves, double-buffered, ONE barrier per K-step ------
// (r9/r15-proven best for QKV dim3(64,12) and FFN1 dim3(64,16).
// r16 lesson: the 4-wave acc[4][4] variant improves LDS-read ratio
// (1.33->2.0 MFMA/read) but HALVES waves/SIMD (16->8 waves/CU) -> net -7us.
// 8-wave wave-tile 64x32 is the right tradeoff at this LDS budget.)
__global__ __launch_bounds__(512) void gemm_dbuf(const ushort_t* __restrict__ A,
                                                 const ushort_t* __restrict__ Bt,
                                                 ushort_t* __restrict__ Out,
                                                 int K, int ldOut,
                                                 const float* __restrict__ bias,
                                                 int relu) {
  __shared__ __align__(16) ushort_t As[2][128 * 64];
  __shared__ __align__(16) ushort_t Bs[2][128 * 64];
  const int tid = threadIdx.x;
  const int lane = tid & 63, wave = tid >> 6;       // 8 waves
  const long row0 = (long)blockIdx.x * 128;         // row-fast
  const long col0 = (long)blockIdx.y * 128;
  const int srow = wave * 16 + (lane >> 3);         // +i*8 -> rows 0..127
  const int scol = (((lane & 7) ^ ((lane >> 3) & 7))) * 8;   // swizzled source
  const ushort_t* Ab = A + (size_t)(row0 + srow) * K + scol;
  const ushort_t* Bb = Bt + (size_t)(col0 + srow) * K + scol;
  const int wm = (wave >> 2) * 64, wn = (wave & 3) * 32;     // wave-tile 64x32
  const int fq = lane >> 4, fl = lane & 15;
  floatx4 acc[4][2] = {};

#pragma unroll
  for (int i = 0; i < 2; i++) {
    gl_lds16(Ab + (size_t)(i * 8) * K, &As[0][(wave * 16 + i * 8) * 64]);
    gl_lds16(Bb + (size_t)(i * 8) * K, &Bs[0][(wave * 16 + i * 8) * 64]);
  }
  __syncthreads();

  int cur = 0;
  for (int k0 = 0; k0 < K; k0 += 64) {
    const int nk = k0 + 64;
    if (nk < K) {
      const int nb = cur ^ 1;
#pragma unroll
      for (int i = 0; i < 2; i++) {
        gl_lds16(Ab + (size_t)(i * 8) * K + nk, &As[nb][(wave * 16 + i * 8) * 64]);
        gl_lds16(Bb + (size_t)(i * 8) * K + nk, &Bs[nb][(wave * 16 + i * 8) * 64]);
      }
    }
#pragma unroll
    for (int ks = 0; ks < 2; ks++) {
      short8 af[4], bf[2];
      const int sl = ((ks * 4 + fq) ^ (fl & 7)) * 8;
#pragma unroll
      for (int i = 0; i < 4; i++)
        af[i] = *(const short8*)&As[cur][(wm + i * 16 + fl) * 64 + sl];
#pragma unroll
      for (int j = 0; j < 2; j++)
        bf[j] = *(const short8*)&Bs[cur][(wn + j * 16 + fl) * 64 + sl];
#pragma unroll
      for (int fi = 0; fi < 4; fi++)
#pragma unroll
        for (int fj = 0; fj < 2; fj++)
          acc[fi][fj] = __builtin_amdgcn_mfma_f32_16x16x32_bf16(af[fi], bf[fj], acc[fi][fj], 0, 0, 0);
    }
    __syncthreads();
    cur ^= 1;
  }
#pragma unroll
  for (int fi = 0; fi < 4; fi++)
#pragma unroll
    for (int fj = 0; fj < 2; fj++) {
      long gcol = col0 + wn + fj * 16 + fl;
      float bv = bias ? bias[gcol] : 0.0f;
#pragma unroll
      for (int r = 0; r < 4; r++) {
        long grow = row0 + wm + fi * 16 + fq * 4 + r;
        float v = acc[fi][fj][r] + bv;
        if (relu) v = fmaxf(v, 0.0f);
        Out[(size_t)grow * ldOut + gcol] = f2b(v);
      }
    }
}

// ---- FFN2 GEMM: 128^2, K=2048, counted-vmcnt schedule (r15-proven) -------
// 1 block/CU regime: B1 -> issue L(t+1) -> vmcnt(4) (drain t-batch only;
// t+1 stays in flight across both barriers + compute) -> B2 -> compute.
__global__ __launch_bounds__(512) void gemm_ffn2(const ushort_t* __restrict__ A,
                                                 const ushort_t* __restrict__ Bt,
                                                 float* __restrict__ Out,
                                                 const float* __restrict__ bias,
                                                 const float* __restrict__ residual) {
  const int K = 2048, ldOut = 512;
  __shared__ __align__(16) ushort_t As[2][128 * 64];
  __shared__ __align__(16) ushort_t Bs[2][128 * 64];
  const int tid = threadIdx.x;
  const int lane = tid & 63, wave = tid >> 6;       // 8 waves
  const long row0 = (long)blockIdx.x * 128;         // row-fast
  const long col0 = (long)blockIdx.y * 128;
  const int srow = wave * 16 + (lane >> 3);
  const int scol = (((lane & 7) ^ ((lane >> 3) & 7))) * 8;
  const ushort_t* Ab = A + (size_t)(row0 + srow) * K + scol;
  const ushort_t* Bb = Bt + (size_t)(col0 + srow) * K + scol;
  const int wm = (wave >> 2) * 64, wn = (wave & 3) * 32;
  const int fq = lane >> 4, fl = lane & 15;
  floatx4 acc[4][2] = {};

  // prologue: issue L(0) into buffer 0 (4 VMEM ops/wave); no sync here --
  // iteration 0's vmcnt+B2 handles it.
#pragma unroll
  for (int i = 0; i < 2; i++) {
    gl_lds16(Ab + (size_t)(i * 8) * K, &As[0][(wave * 16 + i * 8) * 64]);
    gl_lds16(Bb + (size_t)(i * 8) * K, &Bs[0][(wave * 16 + i * 8) * 64]);
  }

  int cur = 0;
  for (int k0 = 0; k0 < K; k0 += 64) {
    __builtin_amdgcn_s_barrier();       // B1: all waves done reading buf[cur^1]
    const int nk = k0 + 64;
    if (nk < K) {                       // issue L(t+1) -> buf[cur^1]
      const int nb = cur ^ 1;
#pragma unroll
      for (int i = 0; i < 2; i++) {
        gl_lds16(Ab + (size_t)(i * 8) * K + nk, &As[nb][(wave * 16 + i * 8) * 64]);
        gl_lds16(Bb + (size_t)(i * 8) * K + nk, &Bs[nb][(wave * 16 + i * 8) * 64]);
      }
      asm volatile("s_waitcnt vmcnt(4)" ::: "memory");  // t-batch landed
    } else {
      asm volatile("s_waitcnt vmcnt(0)" ::: "memory");  // final batch landed
    }
    __builtin_amdgcn_s_barrier();       // B2: buf[cur] staged by all waves
#pragma unroll
    for (int ks = 0; ks < 2; ks++) {
      short8 af[4], bf[2];
      const int sl = ((ks * 4 + fq) ^ (fl & 7)) * 8;
#pragma unroll
      for (int i = 0; i < 4; i++)
        af[i] = *(const short8*)&As[cur][(wm + i * 16 + fl) * 64 + sl];
#pragma unroll
      for (int j = 0; j < 2; j++)
        bf[j] = *(const short8*)&Bs[cur][(wn + j * 16 + fl) * 64 + sl];
#pragma unroll
      for (int fi = 0; fi < 4; fi++)
#pragma unroll
        for (int fj = 0; fj < 2; fj++)
          acc[fi][fj] = __builtin_amdgcn_mfma_f32_16x16x32_bf16(af[fi], bf[fj], acc[fi][fj], 0, 0, 0);
    }
    cur ^= 1;
  }
#pragma unroll
  for (int fi = 0; fi < 4; fi++)
#pragma unroll
    for (int fj = 0; fj < 2; fj++) {
      long gcol = col0 + wn + fj * 16 + fl;
      float bv = bias[gcol];
#pragma unroll
      for (int r = 0; r < 4; r++) {
        long grow = row0 + wm + fi * 16 + fq * 4 + r;
        size_t oi = (size_t)grow * ldOut + gcol;
        Out[oi] = acc[fi][fj][r] + bv + residual[oi];
      }
    }
}

// ---- GEMM 64x64 (FFN2 fallback): fp32 out = acc + bias + residual --------
__global__ __launch_bounds__(256) void gemm_bt64(const ushort_t* __restrict__ A,
                                                 const ushort_t* __restrict__ Bt,
                                                 float* __restrict__ Out,
                                                 int K, int ldOut,
                                                 const float* __restrict__ bias,
                                                 const float* __restrict__ residual) {
  __shared__ __align__(16) ushort_t As[64 * 64];
  __shared__ __align__(16) ushort_t Bs[64 * 64];
  const int tid = threadIdx.x;
  const int lane = tid & 63, wave = tid >> 6;
  const long row0 = (long)blockIdx.x * 64;    // row-fast
  const long col0 = (long)blockIdx.y * 64;
  const int srow = wave * 16 + (lane >> 3);
  const int scol = (((lane & 7) ^ ((lane >> 3) & 7))) * 8;
  const ushort_t* Ab = A + (size_t)(row0 + srow) * K + scol;
  const ushort_t* Bb = Bt + (size_t)(col0 + srow) * K + scol;
  const int wm = (wave >> 1) * 32, wn = (wave & 1) * 32;
  const int fq = lane >> 4, fl = lane & 15;
  floatx4 acc[2][2] = {};

  for (int k0 = 0; k0 < K; k0 += 64) {
    __syncthreads();
#pragma unroll
    for (int i = 0; i < 2; i++) {
      gl_lds16(Ab + (size_t)(i * 8) * K + k0, &As[(wave * 16 + i * 8) * 64]);
      gl_lds16(Bb + (size_t)(i * 8) * K + k0, &Bs[(wave * 16 + i * 8) * 64]);
    }
    __syncthreads();
#pragma unroll
    for (int ks = 0; ks < 2; ks++) {
      short8 af[2], bf[2];
      const int sl = ((ks * 4 + fq) ^ (fl & 7)) * 8;
#pragma unroll
      for (int i = 0; i < 2; i++) {
        af[i] = *(const short8*)&As[(wm + i * 16 + fl) * 64 + sl];
        bf[i] = *(const short8*)&Bs[(wn + i * 16 + fl) * 64 + sl];
      }
#pragma unroll
      for (int fi = 0; fi < 2; fi++)
#pragma unroll
        for (int fj = 0; fj < 2; fj++)
          acc[fi][fj] = __builtin_amdgcn_mfma_f32_16x16x32_bf16(af[fi], bf[fj], acc[fi][fj], 0, 0, 0);
    }
  }
#pragma unroll
  for (int fi = 0; fi < 2; fi++)
#pragma unroll
    for (int fj = 0; fj < 2; fj++) {
      long gcol = col0 + wn + fj * 16 + fl;
      float bv = bias[gcol];
#pragma unroll
      for (int r = 0; r < 4; r++) {
        long grow = row0 + wm + fi * 16 + fq * 4 + r;
        size_t oi = (size_t)grow * ldOut + gcol;
        Out[oi] = acc[fi][fj][r] + bv + residual[oi];
      }
    }
}

// ---- flash attention + residual, 64-row q-tiles, 256 threads (4 waves) ---
// Round-3 proven structure + isolated T5 setprio (r14/r15: 49.2-49.4 us,
// 60 VGPR -- best measured; kept).
__global__ __launch_bounds__(256) void flash_attn(const ushort_t* __restrict__ QKV,
                                                  const float* __restrict__ X,
                                                  float* __restrict__ X1) {
  __shared__ __align__(16) ushort_t kt[2][64 * 72];   // [s][d]
  __shared__ __align__(16) ushort_t vt[2][64 * 72];   // [d][s^swz]
  const int tid = threadIdx.x;
  const int lane = tid & 63, wave = tid >> 6;      // 4 waves
  const int fq = lane >> 4, fl = lane & 15;
  const int g = blockIdx.x >> 5;                   // 0..31
  const int tile = g < 16 ? 31 - g : g - 16;       // balanced pairing
  const int bh = blockIdx.x & 31;
  const int h = bh & 7, b = bh >> 3;
  const int hoff = h * HS_;
  const int q0 = tile * 64;
  const int LD = 3 * C_;                           // 1536
  const int nst = tile + 1;
  const int qg = q0 + wave * 16 + fl;              // q owned by this lane (S^T col)

  short8 qf0, qf1;
  {
    const ushort_t* qp = QKV + (size_t)((size_t)b * T_ + q0 + wave * 16 + fl) * LD + hoff + fq * 8;
    qf0 = *(const short8*)(qp);
    qf1 = *(const short8*)(qp + 32);
  }
  // ones B-fragment for l-accumulation: B[s][d']=1 iff d'==0  -> col fl==0
  short8 of;
  {
    short ob = (fl == 0) ? (short)0x3F80 : (short)0;
#pragma unroll
    for (int i = 0; i < 8; i++) of[i] = ob;
  }
  floatx4 oacc[4] = {};
  floatx4 lacc = {};

  // staging roles: waves 0..1 stage V (transposed), waves 2..3 stage K.
  const int role = tid >> 7;            // 0: V, 1: K
  const int t2 = tid & 127;
  const int sr4 = (t2 >> 3) * 4;        // 0,4,..,60
  const int d0 = (t2 & 7) * 8;          // 0..56
  const ushort_t* sbase = QKV + (size_t)((size_t)b * T_ + sr4) * LD + hoff +
                          (role ? C_ : 2 * C_);   // K at +C_, V at +2C_

  // bpermute source byte-addresses (lane*4)
  const int addrA = ((2 * (fq & 1)) * 16 + fl) * 4;
  const int addrB = addrA + 64;
  const bool lowq = fq < 2;             // dest half selects chunk c=2o vs 2o+1

  // prefetch + stage s-tile 0 into buffer 0
  short8 r0 = *(const short8*)(sbase + d0);
  short8 r1 = *(const short8*)(sbase + LD + d0);
  short8 r2 = *(const short8*)(sbase + 2 * LD + d0);
  short8 r3 = *(const short8*)(sbase + 3 * LD + d0);
  if (role) {
    *(short8*)&kt[0][sr4 * 72 + d0] = r0;
    *(short8*)&kt[0][(sr4 + 1) * 72 + d0] = r1;
    *(short8*)&kt[0][(sr4 + 2) * 72 + d0] = r2;
    *(short8*)&kt[0][(sr4 + 3) * 72 + d0] = r3;
  } else {
#pragma unroll
    for (int i = 0; i < 8; i++) {
      int d = d0 + i;
      int scol = sr4 ^ (8 * (d >> 3));
      unsigned int pkA = ((unsigned int)(ushort_t)r0[i]) |
                         (((unsigned int)(ushort_t)r1[i]) << 16);
      unsigned int pkB = ((unsigned int)(ushort_t)r2[i]) |
                         (((unsigned int)(ushort_t)r3[i]) << 16);
      *(unsigned int*)&vt[0][d * 72 + scol] = pkA;
      *(unsigned int*)&vt[0][d * 72 + scol + 2] = pkB;
    }
  }
  {  // prefetch s-tile 1 (safe even when nst==1: rows 64..127 < T)
    const ushort_t* sp = sbase + (size_t)64 * LD;
    r0 = *(const short8*)(sp + d0);
    r1 = *(const short8*)(sp + LD + d0);
    r2 = *(const short8*)(sp + 2 * LD + d0);
    r3 = *(const short8*)(sp + 3 * LD + d0);
  }

  for (int st = 0; st < nst; st++) {
    __syncthreads();                    // buf[st&1] staged; compute(st-1) done
    const int cur = st & 1;
    if (st + 1 < nst) {                 // stage next tile into other buffer
      const int nb = cur ^ 1;
      if (role) {
        *(short8*)&kt[nb][sr4 * 72 + d0] = r0;
        *(short8*)&kt[nb][(sr4 + 1) * 72 + d0] = r1;
        *(short8*)&kt[nb][(sr4 + 2) * 72 + d0] = r2;
        *(short8*)&kt[nb][(sr4 + 3) * 72 + d0] = r3;
      } else {
#pragma unroll
        for (int i = 0; i < 8; i++) {
          int d = d0 + i;
          int scol = sr4 ^ (8 * (d >> 3));
          unsigned int pkA = ((unsigned int)(ushort_t)r0[i]) |
                             (((unsigned int)(ushort_t)r1[i]) << 16);
          unsigned int pkB = ((unsigned int)(ushort_t)r2[i]) |
                             (((unsigned int)(ushort_t)r3[i]) << 16);
          *(unsigned int*)&vt[nb][d * 72 + scol] = pkA;
          *(unsigned int*)&vt[nb][d * 72 + scol + 2] = pkB;
        }
      }
      if (st + 2 < nst) {               // issue loads for tile st+2
        const ushort_t* sp = sbase + (size_t)(st + 2) * 64 * LD;
        r0 = *(const short8*)(sp + d0);
        r1 = *(const short8*)(sp + LD + d0);
        r2 = *(const short8*)(sp + 2 * LD + d0);
        r3 = *(const short8*)(sp + 3 * LD + d0);
      }
    }

    {
      const int s0 = st * 64;
      floatx4 sacc[4] = {};
      __builtin_amdgcn_s_setprio(1);
#pragma unroll
      for (int fn = 0; fn < 4; fn++) {
        short8 kf0 = *(const short8*)&kt[cur][(fn * 16 + fl) * 72 + fq * 8];
        short8 kf1 = *(const short8*)&kt[cur][(fn * 16 + fl) * 72 + 32 + fq * 8];
        // swapped: A=K rows s, B=Q cols q  ->  D = S^T[s][q]
        sacc[fn] = __builtin_amdgcn_mfma_f32_16x16x32_bf16(kf0, qf0, sacc[fn], 0, 0, 0);
        sacc[fn] = __builtin_amdgcn_mfma_f32_16x16x32_bf16(kf1, qf1, sacc[fn], 0, 0, 0);
      }
      __builtin_amdgcn_s_setprio(0);
      const bool diag = (st == tile);
      unsigned int xc[4][2];            // pair (8*fn + 2*fq + j) of P[q=fl][*]
#pragma unroll
      for (int fn = 0; fn < 4; fn++) {
        float p[4];
#pragma unroll
        for (int r = 0; r < 4; r++) {
          float pv = exp2f(sacc[fn][r]);        // scale folded into wq
          if (diag && (s0 + fn * 16 + fq * 4 + r) > qg) pv = 0.0f;
          p[r] = pv;
        }
        xc[fn][0] = cvtpk(p[0], p[1]);
        xc[fn][1] = cvtpk(p[2], p[3]);
      }
      // in-register layout conversion -> PV A-fragments
      union U8 { unsigned int u[4]; short8 s8; } pu[2];
#pragma unroll
      for (int o = 0; o < 2; o++)
#pragma unroll
        for (int t = 0; t < 4; t++) {
          int ad = (t >> 1) ? addrB : addrA;
          int lo = __builtin_amdgcn_ds_bpermute(ad, (int)xc[2 * o][t & 1]);
          int hi = __builtin_amdgcn_ds_bpermute(ad, (int)xc[2 * o + 1][t & 1]);
          pu[o].u[t] = lowq ? (unsigned int)lo : (unsigned int)hi;
        }
      short8 pf0 = pu[0].s8, pf1 = pu[1].s8;
      __builtin_amdgcn_s_setprio(1);
#pragma unroll
      for (int fn = 0; fn < 4; fn++) {
        int drow = fn * 16 + fl;
        int sw = 8 * (drow >> 3);
        short8 vf0 = *(const short8*)&vt[cur][drow * 72 + ((fq * 8) ^ sw)];
        short8 vf1 = *(const short8*)&vt[cur][drow * 72 + ((32 + fq * 8) ^ sw)];
        oacc[fn] = __builtin_amdgcn_mfma_f32_16x16x32_bf16(pf0, vf0, oacc[fn], 0, 0, 0);
        oacc[fn] = __builtin_amdgcn_mfma_f32_16x16x32_bf16(pf1, vf1, oacc[fn], 0, 0, 0);
      }
      lacc = __builtin_amdgcn_mfma_f32_16x16x32_bf16(pf0, of, lacc, 0, 0, 0);
      lacc = __builtin_amdgcn_mfma_f32_16x16x32_bf16(pf1, of, lacc, 0, 0, 0);
      __builtin_amdgcn_s_setprio(0);
    }
  }
  // X1 = X + O/l
#pragma unroll
  for (int r = 0; r < 4; r++) {
    float lr = __shfl(lacc[r], lane & 48);
    float inv = 1.0f / lr;
    int qgr = q0 + wave * 16 + fq * 4 + r;
#pragma unroll
    for (int fn = 0; fn < 4; fn++) {
      int d = fn * 16 + fl;
      size_t oi = ((size_t)b * T_ + qgr) * C_ + hoff + d;
      X1[oi] = oacc[fn][r] * inv + X[oi];
    }
  }
}

extern "C" void kernel_launch(void* const* d_in, const int* in_sizes, int n_in,
                              void* d_out, int out_size, void* d_ws, size_t ws_size,
                              hipStream_t stream) {
  const float* x  = (const float*)d_in[0];
  const float* wq = (const float*)d_in[1];
  const float* wk = (const float*)d_in[2];
  const float* wv = (const float*)d_in[3];
  const float* w1 = (const float*)d_in[4];
  const float* b1 = (const float*)d_in[5];
  const float* w2 = (const float*)d_in[6];
  const float* b2 = (const float*)d_in[7];
  const float* ln1g = (const float*)d_in[8];
  const float* ln1b = (const float*)d_in[9];
  const float* ln2g = (const float*)d_in[10];
  const float* ln2b = (const float*)d_in[11];
  ushort_t* ws = (ushort_t*)d_ws;

  const size_t SZ = (size_t)M_ * C_;   // 4,194,304 elems
  // ws base: qkvt 786432 | w1t 1048576 | w2t 1048576 | qkv region
  //   split path:   qkv 3*SZ (30.9 MB total); h2=qkv[0,SZ), ff1=qkv[SZ,3SZ)
  //   unsplit path: qkv region 5*SZ (47.7 MB total); ff1=qkv[SZ,5SZ) full-M
  ushort_t* qkvt = ws;
  ushort_t* w1t  = qkvt + 786432;
  ushort_t* w2t  = w1t + 1048576;
  ushort_t* qkv  = w2t + 1048576;
  ushort_t* h2   = qkv;
  ushort_t* ff1  = qkv + SZ;
  ushort_t* h    = (ushort_t*)d_out;   // LN1 out (bf16); dead before flash
  float* x1      = (float*)d_out;      // fp32 residual-1 & final out
  float* outf    = (float*)d_out;

  const size_t need_unsplit = (2883584 + 5 * SZ) * sizeof(ushort_t);  // 47.7 MB

  // fused: weight transposes (2816 blocks) + LN1 (2048 blocks)
  prep_k<<<2816 + M_ / 4, 256, 0, stream>>>(wq, wk, wv, w1, w2, qkvt, w1t, w2t,
                                            x, ln1g, ln1b, h);
  // fused QKV: 128^2 tiles, 8-wave dbuf, 64x12 = 768 blocks (r15-proven)
  gemm_dbuf<<<dim3(64, 12), 512, 0, stream>>>(h, qkvt, qkv, 512, 1536,
                                              nullptr, 0);
  // attention + residual -> x1; 1024 blocks x 256 threads, balanced tiles
  flash_attn<<<B_ * H_ * (T_ / 64), 256, 0, stream>>>(qkv, x, x1);
  ln_k<<<M_ / 4, 256, 0, stream>>>(x1, ln2g, ln2b, h2);
  if (ws_size >= need_unsplit) {
    // FFN1: 8-wave dbuf, 64x16 = 1024 blocks (r15-proven);
    // FFN2: 128^2, 64x4 = 256 blocks, counted-vmcnt schedule (r15)
    gemm_dbuf<<<dim3(64, 16), 512, 0, stream>>>(h2, w1t, ff1, 512, 2048, b1, 1);
    gemm_ffn2<<<dim3(64, 4), 512, 0, stream>>>(ff1, w2t, outf, b2, x1);
  } else {
    for (int p = 0; p < 2; p++) {
      const size_t roff = (size_t)p * 4096;
      gemm_dbuf<<<dim3(32, 16), 512, 0, stream>>>(h2 + roff * C_, w1t, ff1,
                                                  512, 2048, b1, 1);
      gemm_bt64<<<dim3(64, 8), 256, 0, stream>>>(ff1, w2t, outf + roff * C_,
                                                 2048, 512, b2, x1 + roff * C_);
    }
  }
}

// Round 18
// 216.905 us; speedup vs baseline: 1.0570x; 1.0359x over previous
//
#include <hip/hip_runtime.h>

typedef unsigned short ushort_t;
typedef __attribute__((ext_vector_type(8))) short short8;   // 8 bf16 (4 VGPRs)
typedef __attribute__((ext_vector_type(4))) float floatx4;  // 4 fp32 acc

#define B_  4
#define T_  2048
#define C_  512
#define H_  8
#define HS_ 64
#define M_  (B_*T_)          // 8192 rows
// score scale with log2(e) folded in (exp2 path): 512^-0.5 * 1.442695
// folded into wq during prep_k (fp32 multiply pre-bf16-round).
#define SCALE2 0.06376140168547404f

__device__ __forceinline__ float b2f(ushort_t u) {
  union { unsigned int i; float f; } w; w.i = ((unsigned int)u) << 16; return w.f;
}
__device__ __forceinline__ ushort_t f2b(float f) {
  union { float f; unsigned int i; } w; w.f = f;
  unsigned int x = w.i;
  return (ushort_t)((x + 0x7fffu + ((x >> 16) & 1u)) >> 16);  // RNE
}
// v_cvt_pk_bf16_f32: pack two f32 -> u32 of {lo=bf16(a), hi=bf16(b)}
__device__ __forceinline__ unsigned int cvtpk(float a, float b) {
  unsigned int r;
  asm("v_cvt_pk_bf16_f32 %0, %1, %2" : "=v"(r) : "v"(a), "v"(b));
  return r;
}
// async global->LDS, 16B per lane; LDS dest = (uniform base) + lane*16B
__device__ __forceinline__ void gl_lds16(const ushort_t* g, ushort_t* l) {
  __builtin_amdgcn_global_load_lds((const unsigned int*)g, (unsigned int*)l, 16, 0, 0);
}

// ---- fused prep: weight transposes + LN1 in one dispatch ------------------
__global__ __launch_bounds__(256) void prep_k(const float* __restrict__ wq,
                                              const float* __restrict__ wk,
                                              const float* __restrict__ wv,
                                              const float* __restrict__ w1,
                                              const float* __restrict__ w2,
                                              ushort_t* __restrict__ qkvt,
                                              ushort_t* __restrict__ w1t,
                                              ushort_t* __restrict__ w2t,
                                              const float* __restrict__ X,
                                              const float* __restrict__ lg,
                                              const float* __restrict__ lb,
                                              ushort_t* __restrict__ Y) {
  int idx = blockIdx.x;
  if (idx >= 2816) {                    // ---- LN1 part ----
    int wave = threadIdx.x >> 6, lane = threadIdx.x & 63;
    size_t row = (size_t)(idx - 2816) * 4 + wave;
    float v[8], s = 0.f, s2 = 0.f;
#pragma unroll
    for (int i = 0; i < 8; i++) {
      float x = X[row * C_ + lane + 64 * i];
      v[i] = x; s += x; s2 += x * x;
    }
#pragma unroll
    for (int off = 32; off >= 1; off >>= 1) {
      s += __shfl_xor(s, off); s2 += __shfl_xor(s2, off);
    }
    float mu = s * (1.0f / C_);
    float var = s2 * (1.0f / C_) - mu * mu;
    float rs = rsqrtf(var + 1e-5f);
    ushort_t* yr = Y + row * C_;
#pragma unroll
    for (int i = 0; i < 8; i++) {
      int c = lane + 64 * i;
      yr[c] = f2b((v[i] - mu) * rs * lg[c] + lb[c]);
    }
    return;
  }
  // ---- transpose part ----
  __shared__ ushort_t t[32][33];
  const float* in; ushort_t* out; int K, N, bx, by, z = 0;
  float scl = (idx < 256) ? SCALE2 : 1.0f;   // seg 0 == wq
  if (idx < 768) {
    int seg = idx >> 8, li = idx & 255;
    in = seg == 0 ? wq : (seg == 1 ? wk : wv);
    out = qkvt + (size_t)seg * 262144;
    K = 512; N = 64;
    z = li >> 5; li &= 31;
    bx = li & 1; by = li >> 1;
  } else if (idx < 1792) {
    int li = idx - 768;
    in = w1; out = w1t; K = 512; N = 2048;
    bx = li & 63; by = li >> 6;
  } else {
    int li = idx - 1792;
    in = w2; out = w2t; K = 2048; N = 512;
    bx = li & 15; by = li >> 4;
  }
  size_t zoff = (size_t)z * K * N;
  int n0 = bx * 32, k0 = by * 32;
  int tx = threadIdx.x & 31, ty = threadIdx.x >> 5;
#pragma unroll
  for (int i = 0; i < 4; i++)
    t[ty + 8 * i][tx] = f2b(in[zoff + (size_t)(k0 + ty + 8 * i) * N + n0 + tx] * scl);
  __syncthreads();
#pragma unroll
  for (int i = 0; i < 4; i++)
    out[zoff + (size_t)(n0 + ty + 8 * i) * K + k0 + tx] = t[tx][ty + 8 * i];
}

// ---- LayerNorm: wave per row of 512 (fp32 in, bf16 out) ------------------
__global__ __launch_bounds__(256) void ln_k(const float* __restrict__ X,
                                            const float* __restrict__ g,
                                            const float* __restrict__ bb,
                                            ushort_t* __restrict__ Y) {
  int wave = threadIdx.x >> 6, lane = threadIdx.x & 63;
  size_t row = (size_t)blockIdx.x * 4 + wave;
  float v[8], s = 0.f, s2 = 0.f;
#pragma unroll
  for (int i = 0; i < 8; i++) {
    float x = X[row * C_ + lane + 64 * i];
    v[i] = x; s += x; s2 += x * x;
  }
#pragma unroll
  for (int off = 32; off >= 1; off >>= 1) {
    s += __shfl_xor(s, off); s2 += __shfl_xor(s2, off);
  }
  float mu = s * (1.0f / C_);
  float var = s2 * (1.0f / C_) - mu * mu;
  float rs = rsqrtf(var + 1e-5f);
  ushort_t* yr = Y + row * C_;
#pragma unroll
  for (int i = 0; i < 8; i++) {
    int c = lane + 64 * i;
    yr[c] = f2b((v[i] - mu) * rs * g[c] + bb[c]);
  }
}

// ---- GEMM 128x128, 8 waves, double-buffered, ONE barrier per K-step ------
// (r9/r15-proven best for QKV dim3(64,12) and FFN1 dim3(64,16).)
__global__ __launch_bounds__(512) void gemm_dbuf(const ushort_t* __restrict__ A,
                                                 const ushort_t* __restrict__ Bt,
                                                 ushort_t* __restrict__ Out,
                                                 int K, int ldOut,
                                                 const float* __restrict__ bias,
                                                 int relu) {
  __shared__ __align__(16) ushort_t As[2][128 * 64];
  __shared__ __align__(16) ushort_t Bs[2][128 * 64];
  const int tid = threadIdx.x;
  const int lane = tid & 63, wave = tid >> 6;       // 8 waves
  const long row0 = (long)blockIdx.x * 128;         // row-fast
  const long col0 = (long)blockIdx.y * 128;
  const int srow = wave * 16 + (lane >> 3);         // +i*8 -> rows 0..127
  const int scol = (((lane & 7) ^ ((lane >> 3) & 7))) * 8;   // swizzled source
  const ushort_t* Ab = A + (size_t)(row0 + srow) * K + scol;
  const ushort_t* Bb = Bt + (size_t)(col0 + srow) * K + scol;
  const int wm = (wave >> 2) * 64, wn = (wave & 3) * 32;     // wave-tile 64x32
  const int fq = lane >> 4, fl = lane & 15;
  floatx4 acc[4][2] = {};

#pragma unroll
  for (int i = 0; i < 2; i++) {
    gl_lds16(Ab + (size_t)(i * 8) * K, &As[0][(wave * 16 + i * 8) * 64]);
    gl_lds16(Bb + (size_t)(i * 8) * K, &Bs[0][(wave * 16 + i * 8) * 64]);
  }
  __syncthreads();

  int cur = 0;
  for (int k0 = 0; k0 < K; k0 += 64) {
    const int nk = k0 + 64;
    if (nk < K) {
      const int nb = cur ^ 1;
#pragma unroll
      for (int i = 0; i < 2; i++) {
        gl_lds16(Ab + (size_t)(i * 8) * K + nk, &As[nb][(wave * 16 + i * 8) * 64]);
        gl_lds16(Bb + (size_t)(i * 8) * K + nk, &Bs[nb][(wave * 16 + i * 8) * 64]);
      }
    }
#pragma unroll
    for (int ks = 0; ks < 2; ks++) {
      short8 af[4], bf[2];
      const int sl = ((ks * 4 + fq) ^ (fl & 7)) * 8;
#pragma unroll
      for (int i = 0; i < 4; i++)
        af[i] = *(const short8*)&As[cur][(wm + i * 16 + fl) * 64 + sl];
#pragma unroll
      for (int j = 0; j < 2; j++)
        bf[j] = *(const short8*)&Bs[cur][(wn + j * 16 + fl) * 64 + sl];
#pragma unroll
      for (int fi = 0; fi < 4; fi++)
#pragma unroll
        for (int fj = 0; fj < 2; fj++)
          acc[fi][fj] = __builtin_amdgcn_mfma_f32_16x16x32_bf16(af[fi], bf[fj], acc[fi][fj], 0, 0, 0);
    }
    __syncthreads();
    cur ^= 1;
  }
#pragma unroll
  for (int fi = 0; fi < 4; fi++)
#pragma unroll
    for (int fj = 0; fj < 2; fj++) {
      long gcol = col0 + wn + fj * 16 + fl;
      float bv = bias ? bias[gcol] : 0.0f;
#pragma unroll
      for (int r = 0; r < 4; r++) {
        long grow = row0 + wm + fi * 16 + fq * 4 + r;
        float v = acc[fi][fj][r] + bv;
        if (relu) v = fmaxf(v, 0.0f);
        Out[(size_t)grow * ldOut + gcol] = f2b(v);
      }
    }
}

// ---- FFN2 GEMM: 128^2, K=2048, counted-vmcnt schedule (r15-proven) -------
__global__ __launch_bounds__(512) void gemm_ffn2(const ushort_t* __restrict__ A,
                                                 const ushort_t* __restrict__ Bt,
                                                 float* __restrict__ Out,
                                                 const float* __restrict__ bias,
                                                 const float* __restrict__ residual) {
  const int K = 2048, ldOut = 512;
  __shared__ __align__(16) ushort_t As[2][128 * 64];
  __shared__ __align__(16) ushort_t Bs[2][128 * 64];
  const int tid = threadIdx.x;
  const int lane = tid & 63, wave = tid >> 6;       // 8 waves
  const long row0 = (long)blockIdx.x * 128;         // row-fast
  const long col0 = (long)blockIdx.y * 128;
  const int srow = wave * 16 + (lane >> 3);
  const int scol = (((lane & 7) ^ ((lane >> 3) & 7))) * 8;
  const ushort_t* Ab = A + (size_t)(row0 + srow) * K + scol;
  const ushort_t* Bb = Bt + (size_t)(col0 + srow) * K + scol;
  const int wm = (wave >> 2) * 64, wn = (wave & 3) * 32;
  const int fq = lane >> 4, fl = lane & 15;
  floatx4 acc[4][2] = {};

  // prologue: issue L(0) into buffer 0 (4 VMEM ops/wave)
#pragma unroll
  for (int i = 0; i < 2; i++) {
    gl_lds16(Ab + (size_t)(i * 8) * K, &As[0][(wave * 16 + i * 8) * 64]);
    gl_lds16(Bb + (size_t)(i * 8) * K, &Bs[0][(wave * 16 + i * 8) * 64]);
  }

  int cur = 0;
  for (int k0 = 0; k0 < K; k0 += 64) {
    __builtin_amdgcn_s_barrier();       // B1: all waves done reading buf[cur^1]
    const int nk = k0 + 64;
    if (nk < K) {                       // issue L(t+1) -> buf[cur^1]
      const int nb = cur ^ 1;
#pragma unroll
      for (int i = 0; i < 2; i++) {
        gl_lds16(Ab + (size_t)(i * 8) * K + nk, &As[nb][(wave * 16 + i * 8) * 64]);
        gl_lds16(Bb + (size_t)(i * 8) * K + nk, &Bs[nb][(wave * 16 + i * 8) * 64]);
      }
      asm volatile("s_waitcnt vmcnt(4)" ::: "memory");  // t-batch landed
    } else {
      asm volatile("s_waitcnt vmcnt(0)" ::: "memory");  // final batch landed
    }
    __builtin_amdgcn_s_barrier();       // B2: buf[cur] staged by all waves
#pragma unroll
    for (int ks = 0; ks < 2; ks++) {
      short8 af[4], bf[2];
      const int sl = ((ks * 4 + fq) ^ (fl & 7)) * 8;
#pragma unroll
      for (int i = 0; i < 4; i++)
        af[i] = *(const short8*)&As[cur][(wm + i * 16 + fl) * 64 + sl];
#pragma unroll
      for (int j = 0; j < 2; j++)
        bf[j] = *(const short8*)&Bs[cur][(wn + j * 16 + fl) * 64 + sl];
#pragma unroll
      for (int fi = 0; fi < 4; fi++)
#pragma unroll
        for (int fj = 0; fj < 2; fj++)
          acc[fi][fj] = __builtin_amdgcn_mfma_f32_16x16x32_bf16(af[fi], bf[fj], acc[fi][fj], 0, 0, 0);
    }
    cur ^= 1;
  }
#pragma unroll
  for (int fi = 0; fi < 4; fi++)
#pragma unroll
    for (int fj = 0; fj < 2; fj++) {
      long gcol = col0 + wn + fj * 16 + fl;
      float bv = bias[gcol];
#pragma unroll
      for (int r = 0; r < 4; r++) {
        long grow = row0 + wm + fi * 16 + fq * 4 + r;
        size_t oi = (size_t)grow * ldOut + gcol;
        Out[oi] = acc[fi][fj][r] + bv + residual[oi];
      }
    }
}

// ---- GEMM 64x64 (FFN2 fallback): fp32 out = acc + bias + residual --------
__global__ __launch_bounds__(256) void gemm_bt64(const ushort_t* __restrict__ A,
                                                 const ushort_t* __restrict__ Bt,
                                                 float* __restrict__ Out,
                                                 int K, int ldOut,
                                                 const float* __restrict__ bias,
                                                 const float* __restrict__ residual) {
  __shared__ __align__(16) ushort_t As[64 * 64];
  __shared__ __align__(16) ushort_t Bs[64 * 64];
  const int tid = threadIdx.x;
  const int lane = tid & 63, wave = tid >> 6;
  const long row0 = (long)blockIdx.x * 64;    // row-fast
  const long col0 = (long)blockIdx.y * 64;
  const int srow = wave * 16 + (lane >> 3);
  const int scol = (((lane & 7) ^ ((lane >> 3) & 7))) * 8;
  const ushort_t* Ab = A + (size_t)(row0 + srow) * K + scol;
  const ushort_t* Bb = Bt + (size_t)(col0 + srow) * K + scol;
  const int wm = (wave >> 1) * 32, wn = (wave & 1) * 32;
  const int fq = lane >> 4, fl = lane & 15;
  floatx4 acc[2][2] = {};

  for (int k0 = 0; k0 < K; k0 += 64) {
    __syncthreads();
#pragma unroll
    for (int i = 0; i < 2; i++) {
      gl_lds16(Ab + (size_t)(i * 8) * K + k0, &As[(wave * 16 + i * 8) * 64]);
      gl_lds16(Bb + (size_t)(i * 8) * K + k0, &Bs[(wave * 16 + i * 8) * 64]);
    }
    __syncthreads();
#pragma unroll
    for (int ks = 0; ks < 2; ks++) {
      short8 af[2], bf[2];
      const int sl = ((ks * 4 + fq) ^ (fl & 7)) * 8;
#pragma unroll
      for (int i = 0; i < 2; i++) {
        af[i] = *(const short8*)&As[(wm + i * 16 + fl) * 64 + sl];
        bf[i] = *(const short8*)&Bs[(wn + i * 16 + fl) * 64 + sl];
      }
#pragma unroll
      for (int fi = 0; fi < 2; fi++)
#pragma unroll
        for (int fj = 0; fj < 2; fj++)
          acc[fi][fj] = __builtin_amdgcn_mfma_f32_16x16x32_bf16(af[fi], bf[fj], acc[fi][fj], 0, 0, 0);
    }
  }
#pragma unroll
  for (int fi = 0; fi < 2; fi++)
#pragma unroll
    for (int fj = 0; fj < 2; fj++) {
      long gcol = col0 + wn + fj * 16 + fl;
      float bv = bias[gcol];
#pragma unroll
      for (int r = 0; r < 4; r++) {
        long grow = row0 + wm + fi * 16 + fq * 4 + r;
        size_t oi = (size_t)grow * ldOut + gcol;
        Out[oi] = acc[fi][fj][r] + bv + residual[oi];
      }
    }
}

// ---- flash attention + residual, 64-row q-tiles, 256 threads (4 waves) ---
// r15 structure + r18 change: causal-mask VALU hoisted out of the common
// path. Mask can only fire on the diagonal tile (st==tile): there
// s0 == q0, so (s0+fn*16+fq*4+r > qg) reduces to (fn*16+fq*4+r > wave*16+fl);
// for st<tile it provably never fires (s0+63 < q0 <= qg). Split ONLY the
// 16-element p-loop (not MFMA clusters -- r4's whole-body split blew VGPR).
// Branch is wave-uniform. Revert if VGPR > 68 or flash regresses.
__global__ __launch_bounds__(256) void flash_attn(const ushort_t* __restrict__ QKV,
                                                  const float* __restrict__ X,
                                                  float* __restrict__ X1) {
  __shared__ __align__(16) ushort_t kt[2][64 * 72];   // [s][d]
  __shared__ __align__(16) ushort_t vt[2][64 * 72];   // [d][s^swz]
  const int tid = threadIdx.x;
  const int lane = tid & 63, wave = tid >> 6;      // 4 waves
  const int fq = lane >> 4, fl = lane & 15;
  const int g = blockIdx.x >> 5;                   // 0..31
  const int tile = g < 16 ? 31 - g : g - 16;       // balanced pairing
  const int bh = blockIdx.x & 31;
  const int h = bh & 7, b = bh >> 3;
  const int hoff = h * HS_;
  const int q0 = tile * 64;
  const int LD = 3 * C_;                           // 1536
  const int nst = tile + 1;

  short8 qf0, qf1;
  {
    const ushort_t* qp = QKV + (size_t)((size_t)b * T_ + q0 + wave * 16 + fl) * LD + hoff + fq * 8;
    qf0 = *(const short8*)(qp);
    qf1 = *(const short8*)(qp + 32);
  }
  // ones B-fragment for l-accumulation: B[s][d']=1 iff d'==0  -> col fl==0
  short8 of;
  {
    short ob = (fl == 0) ? (short)0x3F80 : (short)0;
#pragma unroll
    for (int i = 0; i < 8; i++) of[i] = ob;
  }
  floatx4 oacc[4] = {};
  floatx4 lacc = {};

  // staging roles: waves 0..1 stage V (transposed), waves 2..3 stage K.
  const int role = tid >> 7;            // 0: V, 1: K
  const int t2 = tid & 127;
  const int sr4 = (t2 >> 3) * 4;        // 0,4,..,60
  const int d0 = (t2 & 7) * 8;          // 0..56
  const ushort_t* sbase = QKV + (size_t)((size_t)b * T_ + sr4) * LD + hoff +
                          (role ? C_ : 2 * C_);   // K at +C_, V at +2C_

  // bpermute source byte-addresses (lane*4)
  const int addrA = ((2 * (fq & 1)) * 16 + fl) * 4;
  const int addrB = addrA + 64;
  const bool lowq = fq < 2;             // dest half selects chunk c=2o vs 2o+1

  // prefetch + stage s-tile 0 into buffer 0
  short8 r0 = *(const short8*)(sbase + d0);
  short8 r1 = *(const short8*)(sbase + LD + d0);
  short8 r2 = *(const short8*)(sbase + 2 * LD + d0);
  short8 r3 = *(const short8*)(sbase + 3 * LD + d0);
  if (role) {
    *(short8*)&kt[0][sr4 * 72 + d0] = r0;
    *(short8*)&kt[0][(sr4 + 1) * 72 + d0] = r1;
    *(short8*)&kt[0][(sr4 + 2) * 72 + d0] = r2;
    *(short8*)&kt[0][(sr4 + 3) * 72 + d0] = r3;
  } else {
#pragma unroll
    for (int i = 0; i < 8; i++) {
      int d = d0 + i;
      int scol = sr4 ^ (8 * (d >> 3));
      unsigned int pkA = ((unsigned int)(ushort_t)r0[i]) |
                         (((unsigned int)(ushort_t)r1[i]) << 16);
      unsigned int pkB = ((unsigned int)(ushort_t)r2[i]) |
                         (((unsigned int)(ushort_t)r3[i]) << 16);
      *(unsigned int*)&vt[0][d * 72 + scol] = pkA;
      *(unsigned int*)&vt[0][d * 72 + scol + 2] = pkB;
    }
  }
  {  // prefetch s-tile 1 (safe even when nst==1: rows 64..127 < T)
    const ushort_t* sp = sbase + (size_t)64 * LD;
    r0 = *(const short8*)(sp + d0);
    r1 = *(const short8*)(sp + LD + d0);
    r2 = *(const short8*)(sp + 2 * LD + d0);
    r3 = *(const short8*)(sp + 3 * LD + d0);
  }

  for (int st = 0; st < nst; st++) {
    __syncthreads();                    // buf[st&1] staged; compute(st-1) done
    const int cur = st & 1;
    if (st + 1 < nst) {                 // stage next tile into other buffer
      const int nb = cur ^ 1;
      if (role) {
        *(short8*)&kt[nb][sr4 * 72 + d0] = r0;
        *(short8*)&kt[nb][(sr4 + 1) * 72 + d0] = r1;
        *(short8*)&kt[nb][(sr4 + 2) * 72 + d0] = r2;
        *(short8*)&kt[nb][(sr4 + 3) * 72 + d0] = r3;
      } else {
#pragma unroll
        for (int i = 0; i < 8; i++) {
          int d = d0 + i;
          int scol = sr4 ^ (8 * (d >> 3));
          unsigned int pkA = ((unsigned int)(ushort_t)r0[i]) |
                             (((unsigned int)(ushort_t)r1[i]) << 16);
          unsigned int pkB = ((unsigned int)(ushort_t)r2[i]) |
                             (((unsigned int)(ushort_t)r3[i]) << 16);
          *(unsigned int*)&vt[nb][d * 72 + scol] = pkA;
          *(unsigned int*)&vt[nb][d * 72 + scol + 2] = pkB;
        }
      }
      if (st + 2 < nst) {               // issue loads for tile st+2
        const ushort_t* sp = sbase + (size_t)(st + 2) * 64 * LD;
        r0 = *(const short8*)(sp + d0);
        r1 = *(const short8*)(sp + LD + d0);
        r2 = *(const short8*)(sp + 2 * LD + d0);
        r3 = *(const short8*)(sp + 3 * LD + d0);
      }
    }

    {
      floatx4 sacc[4] = {};
      __builtin_amdgcn_s_setprio(1);
#pragma unroll
      for (int fn = 0; fn < 4; fn++) {
        short8 kf0 = *(const short8*)&kt[cur][(fn * 16 + fl) * 72 + fq * 8];
        short8 kf1 = *(const short8*)&kt[cur][(fn * 16 + fl) * 72 + 32 + fq * 8];
        // swapped: A=K rows s, B=Q cols q  ->  D = S^T[s][q]
        sacc[fn] = __builtin_amdgcn_mfma_f32_16x16x32_bf16(kf0, qf0, sacc[fn], 0, 0, 0);
        sacc[fn] = __builtin_amdgcn_mfma_f32_16x16x32_bf16(kf1, qf1, sacc[fn], 0, 0, 0);
      }
      __builtin_amdgcn_s_setprio(0);
      unsigned int xc[4][2];            // pair (8*fn + 2*fq + j) of P[q=fl][*]
      if (st != tile) {                 // off-diagonal: mask provably inactive
#pragma unroll
        for (int fn = 0; fn < 4; fn++) {
          float p[4];
#pragma unroll
          for (int r = 0; r < 4; r++) p[r] = exp2f(sacc[fn][r]);
          xc[fn][0] = cvtpk(p[0], p[1]);
          xc[fn][1] = cvtpk(p[2], p[3]);
        }
      } else {                          // diagonal: reduced-threshold mask
        const int wlf = wave * 16 + fl; // == qg - s0 at st==tile
#pragma unroll
        for (int fn = 0; fn < 4; fn++) {
          float p[4];
#pragma unroll
          for (int r = 0; r < 4; r++) {
            float pv = exp2f(sacc[fn][r]);
            if ((fn * 16 + fq * 4 + r) > wlf) pv = 0.0f;
            p[r] = pv;
          }
          xc[fn][0] = cvtpk(p[0], p[1]);
          xc[fn][1] = cvtpk(p[2], p[3]);
        }
      }
      // in-register layout conversion -> PV A-fragments
      union U8 { unsigned int u[4]; short8 s8; } pu[2];
#pragma unroll
      for (int o = 0; o < 2; o++)
#pragma unroll
        for (int t = 0; t < 4; t++) {
          int ad = (t >> 1) ? addrB : addrA;
          int lo = __builtin_amdgcn_ds_bpermute(ad, (int)xc[2 * o][t & 1]);
          int hi = __builtin_amdgcn_ds_bpermute(ad, (int)xc[2 * o + 1][t & 1]);
          pu[o].u[t] = lowq ? (unsigned int)lo : (unsigned int)hi;
        }
      short8 pf0 = pu[0].s8, pf1 = pu[1].s8;
      __builtin_amdgcn_s_setprio(1);
#pragma unroll
      for (int fn = 0; fn < 4; fn++) {
        int drow = fn * 16 + fl;
        int sw = 8 * (drow >> 3);
        short8 vf0 = *(const short8*)&vt[cur][drow * 72 + ((fq * 8) ^ sw)];
        short8 vf1 = *(const short8*)&vt[cur][drow * 72 + ((32 + fq * 8) ^ sw)];
        oacc[fn] = __builtin_amdgcn_mfma_f32_16x16x32_bf16(pf0, vf0, oacc[fn], 0, 0, 0);
        oacc[fn] = __builtin_amdgcn_mfma_f32_16x16x32_bf16(pf1, vf1, oacc[fn], 0, 0, 0);
      }
      lacc = __builtin_amdgcn_mfma_f32_16x16x32_bf16(pf0, of, lacc, 0, 0, 0);
      lacc = __builtin_amdgcn_mfma_f32_16x16x32_bf16(pf1, of, lacc, 0, 0, 0);
      __builtin_amdgcn_s_setprio(0);
    }
  }
  // X1 = X + O/l
#pragma unroll
  for (int r = 0; r < 4; r++) {
    float lr = __shfl(lacc[r], lane & 48);
    float inv = 1.0f / lr;
    int qgr = q0 + wave * 16 + fq * 4 + r;
#pragma unroll
    for (int fn = 0; fn < 4; fn++) {
      int d = fn * 16 + fl;
      size_t oi = ((size_t)b * T_ + qgr) * C_ + hoff + d;
      X1[oi] = oacc[fn][r] * inv + X[oi];
    }
  }
}

extern "C" void kernel_launch(void* const* d_in, const int* in_sizes, int n_in,
                              void* d_out, int out_size, void* d_ws, size_t ws_size,
                              hipStream_t stream) {
  const float* x  = (const float*)d_in[0];
  const float* wq = (const float*)d_in[1];
  const float* wk = (const float*)d_in[2];
  const float* wv = (const float*)d_in[3];
  const float* w1 = (const float*)d_in[4];
  const float* b1 = (const float*)d_in[5];
  const float* w2 = (const float*)d_in[6];
  const float* b2 = (const float*)d_in[7];
  const float* ln1g = (const float*)d_in[8];
  const float* ln1b = (const float*)d_in[9];
  const float* ln2g = (const float*)d_in[10];
  const float* ln2b = (const float*)d_in[11];
  ushort_t* ws = (ushort_t*)d_ws;

  const size_t SZ = (size_t)M_ * C_;   // 4,194,304 elems
  // ws base: qkvt 786432 | w1t 1048576 | w2t 1048576 | qkv region
  //   split path:   qkv 3*SZ (30.9 MB total); h2=qkv[0,SZ), ff1=qkv[SZ,3SZ)
  //   unsplit path: qkv region 5*SZ (47.7 MB total); ff1=qkv[SZ,5SZ) full-M
  ushort_t* qkvt = ws;
  ushort_t* w1t  = qkvt + 786432;
  ushort_t* w2t  = w1t + 1048576;
  ushort_t* qkv  = w2t + 1048576;
  ushort_t* h2   = qkv;
  ushort_t* ff1  = qkv + SZ;
  ushort_t* h    = (ushort_t*)d_out;   // LN1 out (bf16); dead before flash
  float* x1      = (float*)d_out;      // fp32 residual-1 & final out
  float* outf    = (float*)d_out;

  const size_t need_unsplit = (2883584 + 5 * SZ) * sizeof(ushort_t);  // 47.7 MB

  // fused: weight transposes (2816 blocks) + LN1 (2048 blocks)
  prep_k<<<2816 + M_ / 4, 256, 0, stream>>>(wq, wk, wv, w1, w2, qkvt, w1t, w2t,
                                            x, ln1g, ln1b, h);
  // fused QKV: 128^2 tiles, 8-wave dbuf, 64x12 = 768 blocks (r15-proven)
  gemm_dbuf<<<dim3(64, 12), 512, 0, stream>>>(h, qkvt, qkv, 512, 1536,
                                              nullptr, 0);
  // attention + residual -> x1; 1024 blocks x 256 threads, balanced tiles
  flash_attn<<<B_ * H_ * (T_ / 64), 256, 0, stream>>>(qkv, x, x1);
  ln_k<<<M_ / 4, 256, 0, stream>>>(x1, ln2g, ln2b, h2);
  if (ws_size >= need_unsplit) {
    // FFN1: 8-wave dbuf, 64x16 = 1024 blocks (r15-proven);
    // FFN2: 128^2, 64x4 = 256 blocks, counted-vmcnt schedule (r15)
    gemm_dbuf<<<dim3(64, 16), 512, 0, stream>>>(h2, w1t, ff1, 512, 2048, b1, 1);
    gemm_ffn2<<<dim3(64, 4), 512, 0, stream>>>(ff1, w2t, outf, b2, x1);
  } else {
    for (int p = 0; p < 2; p++) {
      const size_t roff = (size_t)p * 4096;
      gemm_dbuf<<<dim3(32, 16), 512, 0, stream>>>(h2 + roff * C_, w1t, ff1,
                                                  512, 2048, b1, 1);
      gemm_bt64<<<dim3(64, 8), 256, 0, stream>>>(ff1, w2t, outf + roff * C_,
                                                 2048, 512, b2, x1 + roff * C_);
    }
  }
}